// Round 3
// baseline (233.900 us; speedup 1.0000x reference)
//
#include <hip/hip_runtime.h>
#include <math.h>

#define N_MESH   5151
#define NB       8
#define TT       2048
#define HID      256
#define NLAYERS  3
#define NCHUNK   16
#define CHUNK    128           // TT / NCHUNK
#define NPAD     5632          // 11*512
#define NBLK1    11            // phase1 n-blocks (512 n each)
#define NBLK3    6             // phase3 n-blocks (1024 n each)
#define TSTR     104           // sigma-table row stride (floats)

// ws layout (floats)
#define WS_DENSITY 0           // 5151
#define WS_SUM     5184        // 1
#define WS_PART    6144        // NB*NBLK3*4*TT = 393216 -> ends 399360
#define WS_P       399360      // NCHUNK*NB*NPAD = 720896 -> ends 1120256
#define WS_Q       1120256     // 720896 -> ends 1841152 (7.4 MB)

// out layout (floats)
#define OUT_BNORM  0           // 16384
#define OUT_DENSB  16384       // 41208
#define OUT_M      57592       // 16384
#define OUT_S0     73976       // 41208
#define OUT_MESHB  115184      // 82416

__device__ __forceinline__ float sigmoid_fast(float x) {
    float e = __expf(-x);
    return __builtin_amdgcn_rcpf(1.0f + e);
}

// ---------------------------------------------------------------------------
// MLP: 8 rows/block, 644 blocks. Rows wave-private (r = rg, rg+4), no barriers.
// k-tiled by 4 with ds_read_b128 h loads.
// ---------------------------------------------------------------------------
__global__ __launch_bounds__(256) void mlp_kernel(
    const float* __restrict__ mesh, const float* __restrict__ Win,
    const float* __restrict__ bin,  const float* __restrict__ Wblk,
    const float* __restrict__ bblk, const float* __restrict__ Wout,
    const float* __restrict__ bout, float* __restrict__ ws_density)
{
    __shared__ float hA[8 * HID];           // 8 KB
    const int tid = threadIdx.x;
    const int lane = tid & 63;
    const int rg   = tid >> 6;
    const int c0   = lane * 4;
    const int row0 = blockIdx.x * 8;

    float4 w0 = *(const float4*)&Win[0 * HID + c0];
    float4 w1 = *(const float4*)&Win[1 * HID + c0];
    float4 bi = *(const float4*)&bin[c0];
#pragma unroll
    for (int j = 0; j < 2; ++j) {
        int r = rg + 4 * j;
        int gr = row0 + r;
        float m0 = 0.f, m1 = 0.f;
        if (gr < N_MESH) { m0 = mesh[2 * gr]; m1 = mesh[2 * gr + 1]; }
        float4 h;
        h.x = fmaxf(fmaf(m0, w0.x, fmaf(m1, w1.x, bi.x)), 0.f);
        h.y = fmaxf(fmaf(m0, w0.y, fmaf(m1, w1.y, bi.y)), 0.f);
        h.z = fmaxf(fmaf(m0, w0.z, fmaf(m1, w1.z, bi.z)), 0.f);
        h.w = fmaxf(fmaf(m0, w0.w, fmaf(m1, w1.w, bi.w)), 0.f);
        *(float4*)&hA[r * HID + c0] = h;
    }

    for (int L = 0; L < NLAYERS; ++L) {
        const float* W = Wblk + (size_t)L * HID * HID;
        float4 a0 = {0.f, 0.f, 0.f, 0.f};
        float4 a1 = {0.f, 0.f, 0.f, 0.f};
#pragma unroll 4
        for (int k = 0; k < HID; k += 4) {
            float4 h0 = *(const float4*)&hA[rg * HID + k];
            float4 h1 = *(const float4*)&hA[(rg + 4) * HID + k];
            float4 wa = *(const float4*)&W[(k + 0) * HID + c0];
            float4 wb = *(const float4*)&W[(k + 1) * HID + c0];
            float4 wc = *(const float4*)&W[(k + 2) * HID + c0];
            float4 wd = *(const float4*)&W[(k + 3) * HID + c0];
            a0.x = fmaf(h0.x, wa.x, a0.x); a0.y = fmaf(h0.x, wa.y, a0.y);
            a0.z = fmaf(h0.x, wa.z, a0.z); a0.w = fmaf(h0.x, wa.w, a0.w);
            a0.x = fmaf(h0.y, wb.x, a0.x); a0.y = fmaf(h0.y, wb.y, a0.y);
            a0.z = fmaf(h0.y, wb.z, a0.z); a0.w = fmaf(h0.y, wb.w, a0.w);
            a0.x = fmaf(h0.z, wc.x, a0.x); a0.y = fmaf(h0.z, wc.y, a0.y);
            a0.z = fmaf(h0.z, wc.z, a0.z); a0.w = fmaf(h0.z, wc.w, a0.w);
            a0.x = fmaf(h0.w, wd.x, a0.x); a0.y = fmaf(h0.w, wd.y, a0.y);
            a0.z = fmaf(h0.w, wd.z, a0.z); a0.w = fmaf(h0.w, wd.w, a0.w);
            a1.x = fmaf(h1.x, wa.x, a1.x); a1.y = fmaf(h1.x, wa.y, a1.y);
            a1.z = fmaf(h1.x, wa.z, a1.z); a1.w = fmaf(h1.x, wa.w, a1.w);
            a1.x = fmaf(h1.y, wb.x, a1.x); a1.y = fmaf(h1.y, wb.y, a1.y);
            a1.z = fmaf(h1.y, wb.z, a1.z); a1.w = fmaf(h1.y, wb.w, a1.w);
            a1.x = fmaf(h1.z, wc.x, a1.x); a1.y = fmaf(h1.z, wc.y, a1.y);
            a1.z = fmaf(h1.z, wc.z, a1.z); a1.w = fmaf(h1.z, wc.w, a1.w);
            a1.x = fmaf(h1.w, wd.x, a1.x); a1.y = fmaf(h1.w, wd.y, a1.y);
            a1.z = fmaf(h1.w, wd.z, a1.z); a1.w = fmaf(h1.w, wd.w, a1.w);
        }
        float4 bb = *(const float4*)&bblk[L * HID + c0];
        {
            float4 h = *(float4*)&hA[rg * HID + c0];
            h.x += fmaxf(a0.x + bb.x, 0.f); h.y += fmaxf(a0.y + bb.y, 0.f);
            h.z += fmaxf(a0.z + bb.z, 0.f); h.w += fmaxf(a0.w + bb.w, 0.f);
            *(float4*)&hA[rg * HID + c0] = h;
        }
        {
            float4 h = *(float4*)&hA[(rg + 4) * HID + c0];
            h.x += fmaxf(a1.x + bb.x, 0.f); h.y += fmaxf(a1.y + bb.y, 0.f);
            h.z += fmaxf(a1.z + bb.z, 0.f); h.w += fmaxf(a1.w + bb.w, 0.f);
            *(float4*)&hA[(rg + 4) * HID + c0] = h;
        }
    }

    float4 wo = *(const float4*)&Wout[c0];
    float bo = bout[0];
    float4 g0 = *(float4*)&hA[rg * HID + c0];
    float4 g1 = *(float4*)&hA[(rg + 4) * HID + c0];
    float p0 = g0.x * wo.x + g0.y * wo.y + g0.z * wo.z + g0.w * wo.w;
    float p1 = g1.x * wo.x + g1.y * wo.y + g1.z * wo.z + g1.w * wo.w;
#pragma unroll
    for (int st = 1; st < 64; st <<= 1) {
        p0 += __shfl_xor(p0, st, 64);
        p1 += __shfl_xor(p1, st, 64);
    }
    if (lane < 2) {
        float sel = (lane == 0) ? p0 : p1;
        int gr = row0 + rg + 4 * lane;
        if (gr < N_MESH) ws_density[gr] = sigmoid_fast(sel + bo);
    }
}

__global__ __launch_bounds__(256) void sum_kernel(const float* __restrict__ density,
                                                  float* __restrict__ sum_out)
{
    __shared__ float red[4];
    float p = 0.f;
    for (int i = threadIdx.x; i < N_MESH; i += 256) p += density[i];
#pragma unroll
    for (int st = 1; st < 64; st <<= 1) p += __shfl_xor(p, st, 64);
    int lane = threadIdx.x & 63, w = threadIdx.x >> 6;
    if (lane == 0) red[w] = p;
    __syncthreads();
    if (threadIdx.x == 0) sum_out[0] = red[0] + red[1] + red[2] + red[3];
}

// ---------------------------------------------------------------------------
// Phase 1: compose affine maps (P,Q) per chunk; sigma from LDS table.
// grid = (NBLK1, NB, NCHUNK), 2 mesh points per thread.
// ---------------------------------------------------------------------------
__global__ __launch_bounds__(256) void scan_phase1(
    const float* __restrict__ dec, const float* __restrict__ y0,
    const float* __restrict__ mesh, float* __restrict__ Pout,
    float* __restrict__ Qout)
{
    __shared__ float hs[CHUNK];
    __shared__ float tab[CHUNK * TSTR];     // 53.2 KB
    const int tid = threadIdx.x;
    const int nb = blockIdx.x, b = blockIdx.y, c = blockIdx.z;
    const int t0 = c * CHUNK;
    const int n0 = nb * 512 + tid;          // and n0+256

    if (tid < CHUNK) hs[tid] = dec[b * TT + t0 + tid];

    int ga[2], gb[2];
#pragma unroll
    for (int q = 0; q < 2; ++q) {
        int n = n0 + q * 256;
        if (n < N_MESH) {
            gb[q] = (int)(mesh[2 * n]     * 100.0f + 0.5f);
            ga[q] = (int)(mesh[2 * n + 1] * 100.0f + 0.5f);
        } else { ga[q] = 0; gb[q] = 0; }
    }
    float hp = (c == 0) ? y0[b] : dec[b * TT + t0 - 1];
    __syncthreads();

    for (int idx = tid; idx < CHUNK * 101; idx += 256) {
        int t = idx / 101;
        int g = idx - t * 101;
        float x = (hs[t] - 0.01f * (float)g) * 1000.0f;
        tab[t * TSTR + g] = sigmoid_fast(x);
    }
    __syncthreads();

    float P0 = 1.f, Q0 = 0.f, P1 = 1.f, Q1 = 0.f;
    for (int tb = 0; tb < CHUNK; tb += 16) {
#pragma unroll
        for (int j = 0; j < 16; ++j) {
            int t = tb + j;
            float ht = hs[t];
            bool inc = (ht >= hp); hp = ht;
            if (__builtin_amdgcn_readfirstlane((int)inc)) {
                float s0 = tab[t * TSTR + ga[0]];
                float s1 = tab[t * TSTR + ga[1]];
                float A0 = 1.f - s0, A1 = 1.f - s1;
                P0 *= A0; Q0 = fmaf(A0, Q0, s0);
                P1 *= A1; Q1 = fmaf(A1, Q1, s1);
            } else {
                float s0 = tab[t * TSTR + gb[0]];
                float s1 = tab[t * TSTR + gb[1]];
                P0 *= s0; Q0 = fmaf(s0, Q0, s0 - 1.f);
                P1 *= s1; Q1 = fmaf(s1, Q1, s1 - 1.f);
            }
        }
    }
    size_t base = ((size_t)(c * NB + b)) * NPAD;
    Pout[base + n0]       = P0;  Qout[base + n0]       = Q0;
    Pout[base + n0 + 256] = P1;  Qout[base + n0 + 256] = Q1;
}

// ---------------------------------------------------------------------------
// Phase 2: chunk-boundary states, stored IN-PLACE into P. grid = (22, NB)
// ---------------------------------------------------------------------------
__global__ __launch_bounds__(256) void scan_phase2(
    const float* __restrict__ s0_in, float* __restrict__ P,
    const float* __restrict__ Q)
{
    const int tid = threadIdx.x;
    const int n = blockIdx.x * 256 + tid;   // < NPAD
    const int b = blockIdx.y;
    float s = (n < N_MESH) ? s0_in[b * N_MESH + n] : 0.f;
#pragma unroll
    for (int c = 0; c < NCHUNK; ++c) {
        size_t idx = ((size_t)(c * NB + b)) * NPAD + n;
        float Pv = P[idx], Qv = Q[idx];
        P[idx] = s;                          // boundary state for chunk c
        s = fmaf(Pv, s, Qv);
    }
}

// ---------------------------------------------------------------------------
// Phase 3: replay chunks from boundary states; 4 mesh points/thread;
// per-wave partials straight to global (no reduction barriers).
// grid = (NBLK3, NB, NCHUNK)
// ---------------------------------------------------------------------------
__global__ __launch_bounds__(256) void scan_phase3(
    const float* __restrict__ dec, const float* __restrict__ y0,
    const float* __restrict__ mesh, const float* __restrict__ density,
    const float* __restrict__ Sstart, float* __restrict__ partials)
{
    __shared__ float hs[CHUNK];
    __shared__ float tab[CHUNK * TSTR];
    const int tid = threadIdx.x;
    const int nb = blockIdx.x, b = blockIdx.y, c = blockIdx.z;
    const int t0 = c * CHUNK;
    const int lane = tid & 63, w = tid >> 6;

    if (tid < CHUNK) hs[tid] = dec[b * TT + t0 + tid];

    int ga[4], gb[4];
    float d[4], s[4];
#pragma unroll
    for (int q = 0; q < 4; ++q) {
        int n = nb * 1024 + q * 256 + tid;
        if (n < N_MESH) {
            gb[q] = (int)(mesh[2 * n]     * 100.0f + 0.5f);
            ga[q] = (int)(mesh[2 * n + 1] * 100.0f + 0.5f);
            d[q]  = density[n];
            s[q]  = Sstart[((size_t)(c * NB + b)) * NPAD + n];
        } else { ga[q] = 0; gb[q] = 0; d[q] = 0.f; s[q] = 0.f; }
    }
    float hp = (c == 0) ? y0[b] : dec[b * TT + t0 - 1];
    __syncthreads();

    for (int idx = tid; idx < CHUNK * 101; idx += 256) {
        int t = idx / 101;
        int g = idx - t * 101;
        float x = (hs[t] - 0.01f * (float)g) * 1000.0f;
        tab[t * TSTR + g] = sigmoid_fast(x);
    }
    __syncthreads();

    float* pout = partials + ((size_t)((b * NBLK3 + nb) * 4 + w)) * TT + t0;

    for (int tb = 0; tb < CHUNK; tb += 16) {
        float v[16];
#pragma unroll
        for (int j = 0; j < 16; ++j) {
            int t = tb + j;
            float ht = hs[t];
            bool inc = (ht >= hp); hp = ht;
            float acc;
            if (__builtin_amdgcn_readfirstlane((int)inc)) {
#pragma unroll
                for (int q = 0; q < 4; ++q) {
                    float sg = tab[t * TSTR + ga[q]];
                    s[q] = fmaf(sg, 1.f - s[q], s[q]);
                }
            } else {
#pragma unroll
                for (int q = 0; q < 4; ++q) {
                    float sg = tab[t * TSTR + gb[q]];
                    s[q] = fmaf(sg, s[q] + 1.f, -1.f);
                }
            }
            acc = d[0] * s[0];
            acc = fmaf(d[1], s[1], acc);
            acc = fmaf(d[2], s[2], acc);
            acc = fmaf(d[3], s[3], acc);
            v[j] = acc;
        }
#pragma unroll
        for (int st = 1; st < 64; st <<= 1) {
#pragma unroll
            for (int j = 0; j < 16; ++j) v[j] += __shfl_xor(v[j], st, 64);
        }
        float outv = v[0];
#pragma unroll
        for (int j = 1; j < 16; ++j) if (lane == j) outv = v[j];
        if (lane < 16) pout[tb + lane] = outv;
    }
}

// ---------------------------------------------------------------------------
// Outputs: m/b_norm from partials, plus all broadcasts/copies.
// ---------------------------------------------------------------------------
__global__ __launch_bounds__(256) void outputs_kernel(
    const float* __restrict__ partials, const float* __restrict__ sum_ptr,
    const float* __restrict__ density, const float* __restrict__ s0,
    const float* __restrict__ mesh, float* __restrict__ out)
{
    int i = blockIdx.x * blockDim.x + threadIdx.x;
    const int NM = NB * TT;                 // 16384
    if (i < NM) {
        int b = i >> 11, t = i & (TT - 1);
        float acc = 0.f;
#pragma unroll
        for (int k = 0; k < NBLK3 * 4; ++k)
            acc += partials[((size_t)(b * NBLK3 * 4 + k)) * TT + t];
        float m = acc / sum_ptr[0];
        out[OUT_M + i] = m;
        out[OUT_BNORM + i] = 0.5f * m + 0.5f;
        return;
    }
    int j = i - NM;
    const int n1 = NB * N_MESH;             // 41208
    if (j < n1) {
        out[OUT_DENSB + j] = density[j % N_MESH];
    } else if (j < 2 * n1) {
        int jj = j - n1;
        out[OUT_S0 + jj] = s0[jj];
    } else if (j < 4 * n1) {
        int jj = j - 2 * n1;
        out[OUT_MESHB + jj] = mesh[jj % (2 * N_MESH)];
    }
}

extern "C" void kernel_launch(void* const* d_in, const int* in_sizes, int n_in,
                              void* d_out, int out_size, void* d_ws, size_t ws_size,
                              hipStream_t stream) {
    const float* dec  = (const float*)d_in[1];
    const float* s0   = (const float*)d_in[2];
    const float* y0   = (const float*)d_in[3];
    const float* mesh = (const float*)d_in[4];
    const float* Win  = (const float*)d_in[5];
    const float* bin  = (const float*)d_in[6];
    const float* Wblk = (const float*)d_in[7];
    const float* bblk = (const float*)d_in[8];
    const float* Wout = (const float*)d_in[9];
    const float* bout = (const float*)d_in[10];
    float* out = (float*)d_out;
    float* ws  = (float*)d_ws;

    float* ws_density  = ws + WS_DENSITY;
    float* ws_sum      = ws + WS_SUM;
    float* ws_partials = ws + WS_PART;
    float* ws_P        = ws + WS_P;
    float* ws_Q        = ws + WS_Q;

    scan_phase1<<<dim3(NBLK1, NB, NCHUNK), 256, 0, stream>>>(
        dec, y0, mesh, ws_P, ws_Q);
    mlp_kernel<<<(N_MESH + 7) / 8, 256, 0, stream>>>(
        mesh, Win, bin, Wblk, bblk, Wout, bout, ws_density);
    sum_kernel<<<1, 256, 0, stream>>>(ws_density, ws_sum);
    scan_phase2<<<dim3(NPAD / 256, NB), 256, 0, stream>>>(s0, ws_P, ws_Q);
    scan_phase3<<<dim3(NBLK3, NB, NCHUNK), 256, 0, stream>>>(
        dec, y0, mesh, ws_density, ws_P, ws_partials);
    {
        int total = NB * TT + NB * N_MESH * 4;   // 181216
        outputs_kernel<<<(total + 255) / 256, 256, 0, stream>>>(
            ws_partials, ws_sum, ws_density, s0, mesh, out);
    }
}

// Round 4
// 131.987 us; speedup vs baseline: 1.7721x; 1.7721x over previous
//
#include <hip/hip_runtime.h>
#include <hip/hip_fp16.h>
#include <math.h>

#define N_MESH   5151
#define NB       8
#define TT       2048
#define HID      256
#define NLAYERS  3
#define NCHUNK   16
#define CHUNK    128           // TT / NCHUNK
#define TSTR     104           // table row stride (ushort)
#define NPAD     6144          // padded mesh count (6 blocks * 1024)
#define NBLK1    6             // phase1 n-blocks (1024 pts each, 4/thread)
#define NBLK3    6             // phase3 n-blocks (1024 pts each, 4/thread)
#define SCAN1_GRID (NBLK1 * NB * NCHUNK)   // 768
#define MLP_ROWS 16
#define MLP_NBLK 322           // ceil(5151/16)

// ws layout (floats)  -- total 2365440 floats = 9.46 MB
#define WS_DENSITY 0           // 5151
#define WS_SUM     5184        // 1
#define WS_PART    6144        // NB*NBLK3*8*TT = 786432 -> ends 792576
#define WS_P       792576      // NCHUNK*NB*NPAD = 786432 -> ends 1579008
#define WS_Q       1579008     // 786432 -> ends 2365440

// out layout (floats)
#define OUT_BNORM  0           // 16384
#define OUT_DENSB  16384       // 41208
#define OUT_M      57592       // 16384
#define OUT_S0     73976       // 41208
#define OUT_MESHB  115184      // 82416

__device__ __forceinline__ float sigmoid_fast(float x) {
    float e = __expf(-x);
    return __builtin_amdgcn_rcpf(1.0f + e);
}

// Build direction-resolved A-table (fp16) + sign array.
// A(t,g) = 1-sigma((h_t-g/100)*1000) on inc steps, sigma(...) on dec steps.
// Both equal 1/(1+exp(y)) with y = +-(1000*h_t - 10*g).
__device__ __forceinline__ void build_table(int tid, const float* hs2,
                                            float* sgv, unsigned short* tab)
{
    int t  = tid >> 1;             // 0..127
    int g0 = (tid & 1) * 52;       // 0 or 52 (covers 104 >= 101)
    float ht = hs2[t + 1];
    float hp = hs2[t];
    bool inc = (ht >= hp);
    if ((tid & 1) == 0) sgv[t] = inc ? 1.0f : -1.0f;
    float bx  = ht * 1000.0f;
    float sb  = inc ? bx : -bx;
    float stp = inc ? -10.0f : 10.0f;
    float y   = fmaf(stp, (float)g0, sb);
    for (int i = 0; i < 52; ++i) {
        float A = __builtin_amdgcn_rcpf(1.0f + __expf(y));
        tab[t * TSTR + g0 + i] = __half_as_ushort(__float2half(A));
        y += stp;
    }
}

// ---------------------------------------------------------------------------
// kernel1: blocks [0,768) = scan phase1 (affine chunk maps P,Q),
//          blocks [768,1090) = density MLP. Block-uniform branch.
// ---------------------------------------------------------------------------
__global__ __launch_bounds__(256) void k1_scan1_mlp(
    const float* __restrict__ dec, const float* __restrict__ y0,
    const float* __restrict__ mesh, const float* __restrict__ Win,
    const float* __restrict__ bin,  const float* __restrict__ Wblk,
    const float* __restrict__ bblk, const float* __restrict__ Wout,
    const float* __restrict__ bout, float* __restrict__ ws_density,
    float* __restrict__ Pout, float* __restrict__ Qout)
{
    __shared__ __align__(16) char smem[32768];
    const int tid = threadIdx.x;

    if (blockIdx.x < SCAN1_GRID) {
        // ------------------ scan phase 1 ------------------
        float* hs2 = (float*)smem;                   // CHUNK+1
        float* sgv = hs2 + 130;                      // CHUNK
        unsigned short* tab = (unsigned short*)(sgv + 128);  // CHUNK*TSTR

        const int sb = blockIdx.x;
        const int nb = sb % NBLK1;
        const int rem = sb / NBLK1;
        const int b = rem & 7;
        const int c = rem >> 3;
        const int t0 = c * CHUNK;

        if (tid < CHUNK) hs2[tid + 1] = dec[b * TT + t0 + tid];
        if (tid == 0) hs2[0] = (c == 0) ? y0[b] : dec[b * TT + t0 - 1];
        __syncthreads();
        build_table(tid, hs2, sgv, tab);
        __syncthreads();

        int ga[4], gb[4];
#pragma unroll
        for (int q = 0; q < 4; ++q) {
            int n = nb * 1024 + q * 256 + tid;
            if (n < N_MESH) {
                gb[q] = (int)(mesh[2 * n]     * 100.0f + 0.5f);
                ga[q] = (int)(mesh[2 * n + 1] * 100.0f + 0.5f);
            } else { ga[q] = 0; gb[q] = 0; }
        }

        float P[4] = {1.f, 1.f, 1.f, 1.f};
        float R[4];
        float gprev = sgv[0];
#pragma unroll
        for (int q = 0; q < 4; ++q) R[q] = -gprev;

        for (int tb = 0; tb < CHUNK; tb += 16) {
#pragma unroll
            for (int j = 0; j < 16; ++j) {
                int t = tb + j;
                float sgt = sgv[t];
                float dl = gprev - sgt;      // 0 or +-2, wave-uniform
                gprev = sgt;
                bool inc = sgt > 0.0f;
                int base = t * TSTR;
#pragma unroll
                for (int q = 0; q < 4; ++q) {
                    int ig = inc ? ga[q] : gb[q];
                    float A = __half2float(__ushort_as_half(tab[base + ig]));
                    float r = R[q] + dl;
                    P[q] *= A;
                    R[q] = r * A;
                }
            }
        }
        size_t basew = ((size_t)(c * NB + b)) * NPAD;
#pragma unroll
        for (int q = 0; q < 4; ++q) {
            int n = nb * 1024 + q * 256 + tid;
            Pout[basew + n] = P[q];
            Qout[basew + n] = R[q] + gprev;   // Q = R + g_last
        }
    } else {
        // ------------------ density MLP ------------------
        float* hA = (float*)smem;            // 16 x 256
        float* wt = hA + MLP_ROWS * HID;     // 16 x 256 (k-tile of W)
        const int mblk = blockIdx.x - SCAN1_GRID;
        const int row0 = mblk * MLP_ROWS;
        const int w = tid >> 6;
        const int lane = tid & 63;
        const int c0 = lane * 4;

        // input layer
        {
            float4 w0 = *(const float4*)&Win[c0];
            float4 w1 = *(const float4*)&Win[HID + c0];
            float4 bi = *(const float4*)&bin[c0];
#pragma unroll
            for (int j = 0; j < 4; ++j) {
                int r = w * 4 + j;
                int gr = row0 + r;
                float m0 = 0.f, m1 = 0.f;
                if (gr < N_MESH) { m0 = mesh[2 * gr]; m1 = mesh[2 * gr + 1]; }
                float4 h;
                h.x = fmaxf(fmaf(m0, w0.x, fmaf(m1, w1.x, bi.x)), 0.f);
                h.y = fmaxf(fmaf(m0, w0.y, fmaf(m1, w1.y, bi.y)), 0.f);
                h.z = fmaxf(fmaf(m0, w0.z, fmaf(m1, w1.z, bi.z)), 0.f);
                h.w = fmaxf(fmaf(m0, w0.w, fmaf(m1, w1.w, bi.w)), 0.f);
                *(float4*)&hA[r * HID + c0] = h;
            }
        }

        const int kk_s = tid >> 4;             // 0..15 (stage row)
        const int cc_s = (tid & 15) * 16;      // stage col base

        for (int L = 0; L < NLAYERS; ++L) {
            const float* W = Wblk + (size_t)L * HID * HID;
            float4 acc[4];
#pragma unroll
            for (int j = 0; j < 4; ++j) acc[j] = make_float4(0.f, 0.f, 0.f, 0.f);

            const float* Ws = W + kk_s * HID + cc_s;
            float4 ld0 = *(const float4*)&Ws[0];
            float4 ld1 = *(const float4*)&Ws[4];
            float4 ld2 = *(const float4*)&Ws[8];
            float4 ld3 = *(const float4*)&Ws[12];

            for (int s = 0; s < 16; ++s) {
                __syncthreads();               // prev compute done reading wt
                float* wd = &wt[kk_s * HID + cc_s];
                *(float4*)&wd[0]  = ld0;
                *(float4*)&wd[4]  = ld1;
                *(float4*)&wd[8]  = ld2;
                *(float4*)&wd[12] = ld3;
                __syncthreads();
                if (s < 15) {
                    const float* Wn = W + (s + 1) * 16 * HID + kk_s * HID + cc_s;
                    ld0 = *(const float4*)&Wn[0];
                    ld1 = *(const float4*)&Wn[4];
                    ld2 = *(const float4*)&Wn[8];
                    ld3 = *(const float4*)&Wn[12];
                }
                int k0 = s * 16;
#pragma unroll
                for (int kk4 = 0; kk4 < 16; kk4 += 4) {
                    float4 wv0 = *(const float4*)&wt[(kk4 + 0) * HID + c0];
                    float4 wv1 = *(const float4*)&wt[(kk4 + 1) * HID + c0];
                    float4 wv2 = *(const float4*)&wt[(kk4 + 2) * HID + c0];
                    float4 wv3 = *(const float4*)&wt[(kk4 + 3) * HID + c0];
#pragma unroll
                    for (int j = 0; j < 4; ++j) {
                        float4 hr = *(const float4*)&hA[(w * 4 + j) * HID + k0 + kk4];
                        acc[j].x = fmaf(hr.x, wv0.x, acc[j].x);
                        acc[j].y = fmaf(hr.x, wv0.y, acc[j].y);
                        acc[j].z = fmaf(hr.x, wv0.z, acc[j].z);
                        acc[j].w = fmaf(hr.x, wv0.w, acc[j].w);
                        acc[j].x = fmaf(hr.y, wv1.x, acc[j].x);
                        acc[j].y = fmaf(hr.y, wv1.y, acc[j].y);
                        acc[j].z = fmaf(hr.y, wv1.z, acc[j].z);
                        acc[j].w = fmaf(hr.y, wv1.w, acc[j].w);
                        acc[j].x = fmaf(hr.z, wv2.x, acc[j].x);
                        acc[j].y = fmaf(hr.z, wv2.y, acc[j].y);
                        acc[j].z = fmaf(hr.z, wv2.z, acc[j].z);
                        acc[j].w = fmaf(hr.z, wv2.w, acc[j].w);
                        acc[j].x = fmaf(hr.w, wv3.x, acc[j].x);
                        acc[j].y = fmaf(hr.w, wv3.y, acc[j].y);
                        acc[j].z = fmaf(hr.w, wv3.z, acc[j].z);
                        acc[j].w = fmaf(hr.w, wv3.w, acc[j].w);
                    }
                }
            }
            __syncthreads();   // all reads of hA done before residual write
            float4 bb = *(const float4*)&bblk[L * HID + c0];
#pragma unroll
            for (int j = 0; j < 4; ++j) {
                int r = w * 4 + j;
                float4 h = *(float4*)&hA[r * HID + c0];
                h.x += fmaxf(acc[j].x + bb.x, 0.f);
                h.y += fmaxf(acc[j].y + bb.y, 0.f);
                h.z += fmaxf(acc[j].z + bb.z, 0.f);
                h.w += fmaxf(acc[j].w + bb.w, 0.f);
                *(float4*)&hA[r * HID + c0] = h;
            }
            __syncthreads();
        }

        // output layer + sigmoid
        float4 wo = *(const float4*)&Wout[c0];
        float bo = bout[0];
        float p[4];
#pragma unroll
        for (int j = 0; j < 4; ++j) {
            float4 h = *(const float4*)&hA[(w * 4 + j) * HID + c0];
            p[j] = h.x * wo.x + h.y * wo.y + h.z * wo.z + h.w * wo.w;
        }
#pragma unroll
        for (int st = 1; st < 64; st <<= 1)
#pragma unroll
            for (int j = 0; j < 4; ++j) p[j] += __shfl_xor(p[j], st, 64);
        if (lane == 0) {
#pragma unroll
            for (int j = 0; j < 4; ++j) {
                int gr = row0 + w * 4 + j;
                if (gr < N_MESH) ws_density[gr] = sigmoid_fast(p[j] + bo);
            }
        }
    }
}

// ---------------------------------------------------------------------------
// kernel2: phase2 (chunk-boundary states, in-place into P) + density sum.
// grid = dim3(25, NB); block (24, y) does sum (y==0) or returns.
// ---------------------------------------------------------------------------
__global__ __launch_bounds__(256) void k2_phase2_sum(
    const float* __restrict__ s0_in, float* __restrict__ P,
    const float* __restrict__ Q, const float* __restrict__ density,
    float* __restrict__ sum_out)
{
    const int tid = threadIdx.x;
    if (blockIdx.x == 24) {
        if (blockIdx.y != 0) return;
        __shared__ float red[4];
        float p = 0.f;
        for (int i = tid; i < N_MESH; i += 256) p += density[i];
#pragma unroll
        for (int st = 1; st < 64; st <<= 1) p += __shfl_xor(p, st, 64);
        int lane = tid & 63, w = tid >> 6;
        if (lane == 0) red[w] = p;
        __syncthreads();
        if (tid == 0) sum_out[0] = red[0] + red[1] + red[2] + red[3];
        return;
    }
    const int n = blockIdx.x * 256 + tid;
    const int b = blockIdx.y;
    float s = (n < N_MESH) ? s0_in[b * N_MESH + n] : 0.f;
#pragma unroll
    for (int c = 0; c < NCHUNK; ++c) {
        size_t idx = ((size_t)(c * NB + b)) * NPAD + n;
        float Pv = P[idx], Qv = Q[idx];
        P[idx] = s;
        s = fmaf(Pv, s, Qv);
    }
}

// ---------------------------------------------------------------------------
// kernel3: phase3 replay. z-form: z *= A, +delta on direction flips.
// partials = sum(d*z) per 32-lane half-wave. grid = 768 (6*8*16).
// ---------------------------------------------------------------------------
__global__ __launch_bounds__(256) void k3_phase3(
    const float* __restrict__ dec, const float* __restrict__ y0,
    const float* __restrict__ mesh, const float* __restrict__ density,
    const float* __restrict__ Sstart, float* __restrict__ partials)
{
    __shared__ __align__(16) char smem[27712];
    float* hs2 = (float*)smem;
    float* sgv = hs2 + 130;
    unsigned short* tab = (unsigned short*)(sgv + 128);

    const int tid = threadIdx.x;
    const int bx = blockIdx.x;
    const int nb = bx % NBLK3;
    const int rem = bx / NBLK3;
    const int b = rem & 7;
    const int c = rem >> 3;
    const int t0 = c * CHUNK;
    const int lane = tid & 63, w = tid >> 6;

    if (tid < CHUNK) hs2[tid + 1] = dec[b * TT + t0 + tid];
    if (tid == 0) hs2[0] = (c == 0) ? y0[b] : dec[b * TT + t0 - 1];
    __syncthreads();
    build_table(tid, hs2, sgv, tab);
    __syncthreads();

    int ga[4], gb[4];
    float d[4], z[4];
    float gprev = sgv[0];
#pragma unroll
    for (int q = 0; q < 4; ++q) {
        int n = nb * 1024 + q * 256 + tid;
        float S = 0.f;
        if (n < N_MESH) {
            gb[q] = (int)(mesh[2 * n]     * 100.0f + 0.5f);
            ga[q] = (int)(mesh[2 * n + 1] * 100.0f + 0.5f);
            d[q]  = density[n];
            S = Sstart[((size_t)(c * NB + b)) * NPAD + n];
        } else { ga[q] = 0; gb[q] = 0; d[q] = 0.f; }
        z[q] = S - gprev;
    }

    float* pout = partials +
        ((size_t)((b * NBLK3 + nb) * 8 + w * 2 + (lane >> 5))) * TT + t0;

    for (int tb = 0; tb < CHUNK; tb += 16) {
        float v[16];
#pragma unroll
        for (int j = 0; j < 16; ++j) {
            int t = tb + j;
            float sgt = sgv[t];
            float dl = gprev - sgt;
            gprev = sgt;
            bool inc = sgt > 0.0f;
            int base = t * TSTR;
            float a0, a1;
#pragma unroll
            for (int q = 0; q < 4; ++q) {
                int ig = inc ? ga[q] : gb[q];
                float A = __half2float(__ushort_as_half(tab[base + ig]));
                z[q] = (z[q] + dl) * A;
            }
            a0 = d[0] * z[0];
            a1 = d[1] * z[1];
            a0 = fmaf(d[2], z[2], a0);
            a1 = fmaf(d[3], z[3], a1);
            v[j] = a0 + a1;
        }
        // depth-5 butterfly: each 32-lane half holds its partial sum
#pragma unroll
        for (int st = 1; st < 32; st <<= 1) {
#pragma unroll
            for (int j = 0; j < 16; ++j) v[j] += __shfl_xor(v[j], st, 64);
        }
        float outv = v[0];
#pragma unroll
        for (int j = 1; j < 16; ++j) if ((lane & 15) == j) outv = v[j];
        if ((lane & 16) == 0) pout[tb + (lane & 15)] = outv;
    }
}

// ---------------------------------------------------------------------------
// kernel4: outputs. m_t = (sum partials + g_t*D)/D ; plus broadcasts/copies.
// ---------------------------------------------------------------------------
__global__ __launch_bounds__(256) void k4_outputs(
    const float* __restrict__ partials, const float* __restrict__ sum_ptr,
    const float* __restrict__ density, const float* __restrict__ s0,
    const float* __restrict__ mesh, const float* __restrict__ dec,
    const float* __restrict__ y0, float* __restrict__ out)
{
    int i = blockIdx.x * blockDim.x + threadIdx.x;
    const int NM = NB * TT;
    if (i < NM) {
        int b = i >> 11, t = i & (TT - 1);
        float h  = dec[b * TT + t];
        float hp = t ? dec[b * TT + t - 1] : y0[b];
        float g  = (h >= hp) ? 1.0f : -1.0f;
        float acc = 0.f;
#pragma unroll 8
        for (int k = 0; k < NBLK3 * 8; ++k)
            acc += partials[((size_t)(b * NBLK3 * 8 + k)) * TT + t];
        float D = sum_ptr[0];
        float m = (acc + g * D) / D;
        out[OUT_M + i] = m;
        out[OUT_BNORM + i] = 0.5f * m + 0.5f;
        return;
    }
    int j = i - NM;
    const int n1 = NB * N_MESH;
    if (j < n1) {
        out[OUT_DENSB + j] = density[j % N_MESH];
    } else if (j < 2 * n1) {
        int jj = j - n1;
        out[OUT_S0 + jj] = s0[jj];
    } else if (j < 4 * n1) {
        int jj = j - 2 * n1;
        out[OUT_MESHB + jj] = mesh[jj % (2 * N_MESH)];
    }
}

extern "C" void kernel_launch(void* const* d_in, const int* in_sizes, int n_in,
                              void* d_out, int out_size, void* d_ws, size_t ws_size,
                              hipStream_t stream) {
    const float* dec  = (const float*)d_in[1];
    const float* s0   = (const float*)d_in[2];
    const float* y0   = (const float*)d_in[3];
    const float* mesh = (const float*)d_in[4];
    const float* Win  = (const float*)d_in[5];
    const float* bin  = (const float*)d_in[6];
    const float* Wblk = (const float*)d_in[7];
    const float* bblk = (const float*)d_in[8];
    const float* Wout = (const float*)d_in[9];
    const float* bout = (const float*)d_in[10];
    float* out = (float*)d_out;
    float* ws  = (float*)d_ws;

    float* ws_density  = ws + WS_DENSITY;
    float* ws_sum      = ws + WS_SUM;
    float* ws_partials = ws + WS_PART;
    float* ws_P        = ws + WS_P;
    float* ws_Q        = ws + WS_Q;

    k1_scan1_mlp<<<SCAN1_GRID + MLP_NBLK, 256, 0, stream>>>(
        dec, y0, mesh, Win, bin, Wblk, bblk, Wout, bout,
        ws_density, ws_P, ws_Q);
    k2_phase2_sum<<<dim3(25, NB), 256, 0, stream>>>(
        s0, ws_P, ws_Q, ws_density, ws_sum);
    k3_phase3<<<SCAN1_GRID, 256, 0, stream>>>(
        dec, y0, mesh, ws_density, ws_P, ws_partials);
    {
        int total = NB * TT + NB * N_MESH * 4;   // 181216
        k4_outputs<<<(total + 255) / 256, 256, 0, stream>>>(
            ws_partials, ws_sum, ws_density, s0, mesh, dec, y0, out);
    }
}